// Round 5
// baseline (4393.390 us; speedup 1.0000x reference)
//
#include <hip/hip_runtime.h>
#include <stdint.h>

#define NLAYER 6
#define BATCH  128
#define HID    256
#define TSEQ   512
#define INFEAT 128
#define DEPTH  8          // h ring-buffer slots per layer (power of 2)
#define OUTN   10

typedef __attribute__((ext_vector_type(8))) short bf16x8;
typedef __attribute__((ext_vector_type(4))) float f32x4;

__device__ __forceinline__ short f2bf(float f) {
  union { float f; uint32_t u; } v; v.f = f;
  uint32_t r = v.u + 0x7fffu + ((v.u >> 16) & 1u);   // RNE
  return (short)(r >> 16);
}
__device__ __forceinline__ float bf2f(uint32_t b) {
  union { uint32_t u; float f; } v; v.u = b << 16;
  return v.f;
}
// convert 8 consecutive fp32 (32B aligned) to a bf16x8 fragment
__device__ __forceinline__ bf16x8 cvt8(const float* p) {
  f32x4 a = *(const f32x4*)p;
  f32x4 b = *(const f32x4*)(p + 4);
  bf16x8 r;
  r[0] = f2bf(a[0]); r[1] = f2bf(a[1]); r[2] = f2bf(a[2]); r[3] = f2bf(a[3]);
  r[4] = f2bf(b[0]); r[5] = f2bf(b[1]); r[6] = f2bf(b[2]); r[7] = f2bf(b[3]);
  return r;
}
__device__ __forceinline__ float sigm(float x)  { return 1.0f / (1.0f + __expf(-x)); }
__device__ __forceinline__ float tanhff(float x){ return 1.0f - 2.0f / (__expf(2.0f * x) + 1.0f); }

// Device-coherent (L2-bypassing) accesses meet at the coherent point; no
// acquire/release cache maintenance ops needed anywhere in the hot loop.
__device__ __forceinline__ bf16x8 load_frag_dc(const uint16_t* p) {
  union { unsigned long long q[2]; bf16x8 v; } u;
  u.q[0] = __hip_atomic_load((const unsigned long long*)p,
                             __ATOMIC_RELAXED, __HIP_MEMORY_SCOPE_AGENT);
  u.q[1] = __hip_atomic_load((const unsigned long long*)(p + 4),
                             __ATOMIC_RELAXED, __HIP_MEMORY_SCOPE_AGENT);
  return u.v;
}
__device__ __forceinline__ void store_u16_dc(uint16_t* p, uint16_t v) {
  __hip_atomic_store(p, v, __ATOMIC_RELAXED, __HIP_MEMORY_SCOPE_AGENT);
}
__device__ __forceinline__ void store_u8_dc(uint8_t* p, uint8_t v) {
  __hip_atomic_store(p, v, __ATOMIC_RELAXED, __HIP_MEMORY_SCOPE_AGENT);
}
// 32 producer flags (u8 each, 32B record). Full when every byte == 1.
__device__ __forceinline__ bool rec_full(const uint8_t* f) {
  unsigned long long a = __hip_atomic_load((const unsigned long long*)f,
                                           __ATOMIC_RELAXED, __HIP_MEMORY_SCOPE_AGENT);
  unsigned long long b = __hip_atomic_load((const unsigned long long*)(f + 8),
                                           __ATOMIC_RELAXED, __HIP_MEMORY_SCOPE_AGENT);
  unsigned long long c = __hip_atomic_load((const unsigned long long*)(f + 16),
                                           __ATOMIC_RELAXED, __HIP_MEMORY_SCOPE_AGENT);
  unsigned long long d = __hip_atomic_load((const unsigned long long*)(f + 24),
                                           __ATOMIC_RELAXED, __HIP_MEMORY_SCOPE_AGENT);
  return ((a & b & c & d) == 0x0101010101010101ULL);
}

// 192 blocks x 512 threads: 6 layers x 4 batch-slices(32) x 8 unit-groups(32).
// 8 waves per block: wm (16-row half) x wu (16-unit half) x ks (K half).
// K-split: each wave holds only half the K-depth of W_ih/W_hh -> 128 VGPRs of
// weights, leaving room to hoist all A-fragment loads (the round-4 bottleneck).
// Partial accs summed via LDS; ks=0 waves do gates/state/stores/flags.
__global__ void __launch_bounds__(512, 2)
lstm_pipeline(const float* __restrict__ xin, const float* __restrict__ h0,
              const float* __restrict__ c0,  const float* __restrict__ wih,
              const float* __restrict__ whh, const float* __restrict__ bih,
              const float* __restrict__ bhh, const float* __restrict__ fcw,
              const float* __restrict__ fcb, float* __restrict__ out,
              uint8_t* flags, uint16_t* hbuf)
{
  // ---- id decode: siblings of one (layer,bslice) share bid%8 (= likely XCD) ----
  const int bid  = blockIdx.x;
  const int xcd  = bid & 7;
  const int slot = bid >> 3;                 // 0..23
  const int grp  = (slot >> 3) * 8 + xcd;    // 0..23  (layer,bslice) group
  const int cg   = slot & 7;                 // unit-group 0..7
  const int l  = grp >> 2;
  const int bs = grp & 3;

  const int tid  = threadIdx.x;
  const int wv   = tid >> 6, lane = tid & 63;
  const int wm   = wv & 1;          // 16-batch-row half
  const int wu   = (wv >> 1) & 1;   // 16-unit half
  const int ks   = wv >> 2;         // K half (kk 0..3 or 4..7)
  const int l15  = lane & 15, l4 = lane >> 4;

  // ---- resident weight fragments: wf[mat][gate][kk4], global kk = ks*4+kk4 ----
  bf16x8 wf[2][4][4];
  float  bias[4] = {0.f, 0.f, 0.f, 0.f};
  {
    const float* Wl[2] = { wih + (size_t)l * 1024 * 256,
                           whh + (size_t)l * 1024 * 256 };
#pragma unroll
    for (int mat = 0; mat < 2; ++mat) {
#pragma unroll
      for (int gt = 0; gt < 4; ++gt) {
        const int Rg = gt * 256 + cg * 32 + wu * 16 + l15;  // gate-row (B j = lane&15)
        const float* rp = Wl[mat] + (size_t)Rg * 256 + ks * 128 + l4 * 8;
#pragma unroll
        for (int kk4 = 0; kk4 < 4; ++kk4)
          wf[mat][gt][kk4] = cvt8(rp + kk4 * 32);
      }
    }
    if (ks == 0) {
#pragma unroll
      for (int gt = 0; gt < 4; ++gt) {
        const int Rg = gt * 256 + cg * 32 + wu * 16 + l15;
        bias[gt] = bih[l * 1024 + Rg] + bhh[l * 1024 + Rg];
      }
    }
  }

  const int ucol  = cg * 32 + wu * 16 + l15;   // this lane's hidden unit (C/D col)
  const int mrowA = bs * 32 + wm * 16 + l15;   // A-fragment batch row
  const int mrow0 = bs * 32 + wm * 16 + l4*4;  // C/D batch-row base (+j)

  float c[4] = {0.f, 0.f, 0.f, 0.f};
  if (ks == 0) {
#pragma unroll
    for (int j = 0; j < 4; ++j)
      c[j] = c0[((size_t)l * BATCH + (mrow0 + j)) * HID + ucol];
  }

  // flag records: flags[grp][t] = 32B record of 32 u8 flags (8 cg x 4 tiles)
  const uint8_t* fXr = (l > 0) ? flags + ((size_t)((l - 1) * 4 + bs) * TSEQ) * 32 : nullptr;
  uint8_t*       fOr = flags + ((size_t)grp * TSEQ) * 32;
  const uint8_t* fCr = (l < 5) ? flags + ((size_t)((l + 1) * 4 + bs) * TSEQ) * 32 : nullptr;

  const uint16_t* hbL = hbuf + (size_t)l * DEPTH * BATCH * HID;
  const uint16_t* hbX = (l > 0) ? hbuf + (size_t)(l - 1) * DEPTH * BATCH * HID : nullptr;
  uint16_t*       hbO = hbuf + (size_t)l * DEPTH * BATCH * HID;

  // LDS partial-acc exchange: [parity][tile(wm*2+wu)][gate][lane], b128-contiguous
  __shared__ f32x4 lred[2][4][4][64];

  for (int t = 0; t < TSEQ; ++t) {
    // ---- joint rendezvous: x flag (layer below, t) + h flag (own, t-1) ----
    {
      bool needx = (l > 0), needh = (t > 0);
      const uint8_t* fx = needx ? fXr + (size_t)t * 32 : nullptr;
      const uint8_t* fo = needh ? fOr + (size_t)(t - 1) * 32 : nullptr;
      while (needx || needh) {
        if (needx && rec_full(fx)) needx = false;
        if (needh && rec_full(fo)) needh = false;
      }
    }

    f32x4 acc[4];
#pragma unroll
    for (int gt = 0; gt < 4; ++gt) {
      f32x4 a = {bias[gt], bias[gt], bias[gt], bias[gt]};
      acc[gt] = a;
    }

    // ---- A-fragment loads (hoistable: only 8 x 16B live at once) ----
    bf16x8 ah[4];
    if (t == 0) {
      const float* hp = h0 + ((size_t)l * BATCH + mrowA) * HID + ks * 128 + l4 * 8;
#pragma unroll
      for (int kk4 = 0; kk4 < 4; ++kk4) ah[kk4] = cvt8(hp + kk4 * 32);
    } else {
      const uint16_t* hp = hbL + ((size_t)((t - 1) & (DEPTH - 1)) * BATCH + mrowA) * HID
                         + ks * 128 + l4 * 8;
#pragma unroll
      for (int kk4 = 0; kk4 < 4; ++kk4) ah[kk4] = load_frag_dc(hp + kk4 * 32);
    }

    if (l == 0) {
      // ks=0 covers global kk 0..3 = the full 128 real input features;
      // ks=1's K-range is the zero-pad (contribution is exactly zero) -> skip.
      if (ks == 0) {
        const float* xp = xin + ((size_t)mrowA * TSEQ + t) * INFEAT + l4 * 8;
        bf16x8 ax[4];
#pragma unroll
        for (int kk4 = 0; kk4 < 4; ++kk4) ax[kk4] = cvt8(xp + kk4 * 32);
#pragma unroll
        for (int kk4 = 0; kk4 < 4; ++kk4)
#pragma unroll
          for (int gt = 0; gt < 4; ++gt)
            acc[gt] = __builtin_amdgcn_mfma_f32_16x16x32_bf16(ax[kk4], wf[0][gt][kk4], acc[gt], 0, 0, 0);
      }
    } else {
      const uint16_t* hp = hbX + ((size_t)(t & (DEPTH - 1)) * BATCH + mrowA) * HID
                         + ks * 128 + l4 * 8;
      bf16x8 ax[4];
#pragma unroll
      for (int kk4 = 0; kk4 < 4; ++kk4) ax[kk4] = load_frag_dc(hp + kk4 * 32);
#pragma unroll
      for (int kk4 = 0; kk4 < 4; ++kk4)
#pragma unroll
        for (int gt = 0; gt < 4; ++gt)
          acc[gt] = __builtin_amdgcn_mfma_f32_16x16x32_bf16(ax[kk4], wf[0][gt][kk4], acc[gt], 0, 0, 0);
    }

#pragma unroll
    for (int kk4 = 0; kk4 < 4; ++kk4)
#pragma unroll
      for (int gt = 0; gt < 4; ++gt)
        acc[gt] = __builtin_amdgcn_mfma_f32_16x16x32_bf16(ah[kk4], wf[1][gt][kk4], acc[gt], 0, 0, 0);

    // ---- K-half reduction via LDS (double-buffered by t parity) ----
    if (ks == 1) {
#pragma unroll
      for (int gt = 0; gt < 4; ++gt)
        lred[t & 1][wm * 2 + wu][gt][lane] = acc[gt];
    }
    __syncthreads();

    if (ks == 0) {
#pragma unroll
      for (int gt = 0; gt < 4; ++gt) {
        f32x4 p = lred[t & 1][wm * 2 + wu][gt][lane];
        acc[gt][0] += p[0]; acc[gt][1] += p[1]; acc[gt][2] += p[2]; acc[gt][3] += p[3];
      }

      // backpressure: consumer layer must be done with the slot we overwrite
      if (l < 5 && t >= DEPTH) {
        const uint8_t* fc = fCr + (size_t)(t - DEPTH) * 32;
        while (!rec_full(fc)) __builtin_amdgcn_s_sleep(2);
      }

      // gates, state update, h store (device-coherent)
      uint16_t* op = hbO + (size_t)(t & (DEPTH - 1)) * BATCH * HID;
#pragma unroll
      for (int j = 0; j < 4; ++j) {
        float iv = sigm(acc[0][j]);
        float fv = sigm(acc[1][j]);
        float gv = tanhff(acc[2][j]);
        float ov = sigm(acc[3][j]);
        float cc = fv * c[j] + iv * gv;
        c[j] = cc;
        float hv = ov * tanhff(cc);
        store_u16_dc(op + (size_t)(mrow0 + j) * HID + ucol, (uint16_t)f2bf(hv));
      }
      // per-wave drain then per-wave flag: no barrier on the signal path
      asm volatile("s_waitcnt vmcnt(0)" ::: "memory");
      if (lane == 0)
        store_u8_dc(fOr + (size_t)t * 32 + (cg * 4 + wm * 2 + wu), (uint8_t)1);
    }
  }

  // ---------------- FC head: one WG per batch slice ----------------
  if (l == 5 && cg == 0) {
    const uint8_t* fl = fOr + (size_t)(TSEQ - 1) * 32;
    while (!rec_full(fl)) __builtin_amdgcn_s_sleep(1);
    const uint16_t* hp = hbL + (size_t)((TSEQ - 1) & (DEPTH - 1)) * BATCH * HID;
    for (int p = tid; p < 32 * OUTN; p += 512) {
      const int mr = bs * 32 + p / OUTN, oc = p % OUTN;
      float a = fcb[oc];
      const uint16_t* hr = hp + (size_t)mr * HID;
      const float* wr = fcw + oc * HID;
#pragma unroll
      for (int uu = 0; uu < HID; uu += 4) {
        unsigned long long q = __hip_atomic_load((const unsigned long long*)(hr + uu),
                                                 __ATOMIC_RELAXED, __HIP_MEMORY_SCOPE_AGENT);
        a += bf2f((uint32_t)(q & 0xffff))         * wr[uu]
           + bf2f((uint32_t)((q >> 16) & 0xffff)) * wr[uu + 1]
           + bf2f((uint32_t)((q >> 32) & 0xffff)) * wr[uu + 2]
           + bf2f((uint32_t)(q >> 48))            * wr[uu + 3];
      }
      out[mr * OUTN + oc] = a;
    }
  }
}

extern "C" void kernel_launch(void* const* d_in, const int* in_sizes, int n_in,
                              void* d_out, int out_size, void* d_ws, size_t ws_size,
                              hipStream_t stream) {
  const float* xin = (const float*)d_in[0];
  const float* h0  = (const float*)d_in[1];
  const float* c0  = (const float*)d_in[2];
  const float* wih = (const float*)d_in[3];
  const float* whh = (const float*)d_in[4];
  const float* bih = (const float*)d_in[5];
  const float* bhh = (const float*)d_in[6];
  const float* fcw = (const float*)d_in[7];
  const float* fcb = (const float*)d_in[8];
  float* out = (float*)d_out;

  // flags: 24 groups x 512 t x 32 u8 = 384 KB, zeroed each launch
  uint8_t* flags = (uint8_t*)d_ws;
  const size_t flagBytes = (size_t)24 * TSEQ * 32;
  uint16_t* hbuf = (uint16_t*)((char*)d_ws + 0x80000);   // 512KB offset; 3.1MB ring

  hipMemsetAsync(d_ws, 0, flagBytes, stream);
  lstm_pipeline<<<dim3(192), dim3(512), 0, stream>>>(
      xin, h0, c0, wih, whh, bih, bhh, fcw, fcb, out, flags, hbuf);
}

// Round 6
// 3418.544 us; speedup vs baseline: 1.2852x; 1.2852x over previous
//
#include <hip/hip_runtime.h>
#include <stdint.h>

#define NLAYER 6
#define BATCH  128
#define HID    256
#define TSEQ   512
#define INFEAT 128
#define DEPTH  8          // h ring-buffer slots per layer (power of 2)
#define OUTN   10

typedef __attribute__((ext_vector_type(8))) short bf16x8;
typedef __attribute__((ext_vector_type(4))) float f32x4;

__device__ __forceinline__ short f2bf(float f) {
  union { float f; uint32_t u; } v; v.f = f;
  uint32_t r = v.u + 0x7fffu + ((v.u >> 16) & 1u);   // RNE
  return (short)(r >> 16);
}
__device__ __forceinline__ float bf2f(uint32_t b) {
  union { uint32_t u; float f; } v; v.u = b << 16;
  return v.f;
}
// convert 8 consecutive fp32 (32B aligned) to a bf16x8 fragment
__device__ __forceinline__ bf16x8 cvt8(const float* p) {
  f32x4 a = *(const f32x4*)p;
  f32x4 b = *(const f32x4*)(p + 4);
  bf16x8 r;
  r[0] = f2bf(a[0]); r[1] = f2bf(a[1]); r[2] = f2bf(a[2]); r[3] = f2bf(a[3]);
  r[4] = f2bf(b[0]); r[5] = f2bf(b[1]); r[6] = f2bf(b[2]); r[7] = f2bf(b[3]);
  return r;
}
__device__ __forceinline__ float sigm(float x)  { return 1.0f / (1.0f + __expf(-x)); }
__device__ __forceinline__ float tanhff(float x){ return 1.0f - 2.0f / (__expf(2.0f * x) + 1.0f); }

// Device-coherent (L2-bypassing) accesses meet at the coherent point; no
// acquire/release cache-maintenance ops needed anywhere in the hot loop.
__device__ __forceinline__ bf16x8 load_frag_dc(const uint16_t* p) {
  union { unsigned long long q[2]; bf16x8 v; } u;
  u.q[0] = __hip_atomic_load((const unsigned long long*)p,
                             __ATOMIC_RELAXED, __HIP_MEMORY_SCOPE_AGENT);
  u.q[1] = __hip_atomic_load((const unsigned long long*)(p + 4),
                             __ATOMIC_RELAXED, __HIP_MEMORY_SCOPE_AGENT);
  return u.v;
}
__device__ __forceinline__ void store_u16_dc(uint16_t* p, uint16_t v) {
  __hip_atomic_store(p, v, __ATOMIC_RELAXED, __HIP_MEMORY_SCOPE_AGENT);
}
__device__ __forceinline__ void store_u8_dc(uint8_t* p, uint8_t v) {
  __hip_atomic_store(p, v, __ATOMIC_RELAXED, __HIP_MEMORY_SCOPE_AGENT);
}
// half-record: 16 u8 producer flags (one wm-half). Full when all bytes == 1.
__device__ __forceinline__ bool rec_half(const uint8_t* f) {
  unsigned long long a = __hip_atomic_load((const unsigned long long*)f,
                                           __ATOMIC_RELAXED, __HIP_MEMORY_SCOPE_AGENT);
  unsigned long long b = __hip_atomic_load((const unsigned long long*)(f + 8),
                                           __ATOMIC_RELAXED, __HIP_MEMORY_SCOPE_AGENT);
  return ((a & b) == 0x0101010101010101ULL);
}

// 192 blocks x 256 threads: 6 layers x 4 batch-slices(32 rows) x 8 cg(32 units).
// 4 independent waves per block: wm (16-row half) x wu (16-unit half).
// W_hh: register-resident (128 VGPR). W_ih: LDS (64 KB) -> ~100 free VGPRs so
// all 16 A-fragments hoist and their coherent-point loads pipeline.
// No per-step __syncthreads: per-wave flags after wave-local vmcnt drain.
__global__ void __launch_bounds__(256, 1)
lstm_pipeline(const float* __restrict__ xin, const float* __restrict__ h0,
              const float* __restrict__ c0,  const float* __restrict__ wih,
              const float* __restrict__ whh, const float* __restrict__ bih,
              const float* __restrict__ bhh, const float* __restrict__ fcw,
              const float* __restrict__ fcb, float* __restrict__ out,
              uint8_t* flags, uint16_t* hbuf)
{
  // ---- id decode: siblings of one (layer,bslice) share bid%8 (= likely XCD) ----
  const int bid  = blockIdx.x;
  const int xcd  = bid & 7;
  const int slot = bid >> 3;                 // 0..23
  const int grp  = (slot >> 3) * 8 + xcd;    // 0..23  (layer,bslice) group
  const int cg   = slot & 7;                 // unit-group 0..7
  const int l  = grp >> 2;
  const int bs = grp & 3;

  const int tid  = threadIdx.x;
  const int wv   = tid >> 6, lane = tid & 63;
  const int wm   = wv & 1,  wu   = wv >> 1;
  const int l15  = lane & 15, l4 = lane >> 4;

  // ---- W_ih slice -> LDS, fragment layout [gt][kk][u5][l4], 16B each ----
  __shared__ bf16x8 lds_wih[4096];           // 4 x 8 x 32 x 4 = 64 KB
  {
    const float* W = wih + (size_t)l * 1024 * 256;
    for (int lin = tid; lin < 4096; lin += 256) {
      const int l4s = lin & 3;
      const int u5  = (lin >> 2) & 31;
      const int kk  = (lin >> 7) & 7;
      const int gt  = lin >> 10;
      const int row = gt * 256 + cg * 32 + u5;
      lds_wih[lin] = cvt8(W + (size_t)row * 256 + kk * 32 + l4s * 8);
    }
  }

  // ---- resident W_hh fragments: wh[gate][kk] (128 VGPR) ----
  bf16x8 wh[4][8];
  float  bias[4];
  {
    const float* W = whh + (size_t)l * 1024 * 256;
#pragma unroll
    for (int gt = 0; gt < 4; ++gt) {
      const int Rg = gt * 256 + cg * 32 + wu * 16 + l15;  // gate-row (B col = lane&15)
      const float* rp = W + (size_t)Rg * 256 + l4 * 8;
#pragma unroll
      for (int kk = 0; kk < 8; ++kk)
        wh[gt][kk] = cvt8(rp + kk * 32);
      bias[gt] = bih[l * 1024 + Rg] + bhh[l * 1024 + Rg];
    }
  }
  __syncthreads();   // LDS W_ih ready (only barrier in the kernel)

  const int ucol  = cg * 32 + wu * 16 + l15;   // this lane's hidden unit (C/D col)
  const int mrowA = bs * 32 + wm * 16 + l15;   // A-fragment batch row
  const int mrow0 = bs * 32 + wm * 16 + l4*4;  // C/D batch-row base (+j)

  float c[4];
#pragma unroll
  for (int j = 0; j < 4; ++j)
    c[j] = c0[((size_t)l * BATCH + (mrow0 + j)) * HID + ucol];

  // flag records: flags[grp][t] = 32 u8 (idx = wm*16 + cg*2 + wu)
  const uint8_t* fXr = (l > 0) ? flags + ((size_t)((l - 1) * 4 + bs) * TSEQ) * 32 : nullptr;
  uint8_t*       fOr = flags + ((size_t)grp * TSEQ) * 32;
  const uint8_t* fCr = (l < 5) ? flags + ((size_t)((l + 1) * 4 + bs) * TSEQ) * 32 : nullptr;

  const uint16_t* hbL = hbuf + (size_t)l * DEPTH * BATCH * HID;
  const uint16_t* hbX = (l > 0) ? hbuf + (size_t)(l - 1) * DEPTH * BATCH * HID : nullptr;
  uint16_t*       hbO = hbuf + (size_t)l * DEPTH * BATCH * HID;

  const int fidx = wm * 16 + cg * 2 + wu;

  for (int t = 0; t < TSEQ; ++t) {
    // ---- joint rendezvous on wm-half records: one detect latency ----
    {
      bool needx = (l > 0), needh = (t > 0);
      const uint8_t* fx = needx ? fXr + (size_t)t * 32 + wm * 16 : nullptr;
      const uint8_t* fo = needh ? fOr + (size_t)(t - 1) * 32 + wm * 16 : nullptr;
      while (needx || needh) {
        if (needx && rec_half(fx)) needx = false;
        if (needh && rec_half(fo)) needh = false;
      }
    }

    // ---- hoisted A-fragment loads: all issue back-to-back, pipelined ----
    bf16x8 ah[8];
    if (t == 0) {
      const float* hp = h0 + ((size_t)l * BATCH + mrowA) * HID + l4 * 8;
#pragma unroll
      for (int kk = 0; kk < 8; ++kk) ah[kk] = cvt8(hp + kk * 32);
    } else {
      const uint16_t* hp = hbL + ((size_t)((t - 1) & (DEPTH - 1)) * BATCH + mrowA) * HID + l4 * 8;
#pragma unroll
      for (int kk = 0; kk < 8; ++kk) ah[kk] = load_frag_dc(hp + kk * 32);
    }

    f32x4 acc[4];
#pragma unroll
    for (int gt = 0; gt < 4; ++gt) {
      f32x4 a = {bias[gt], bias[gt], bias[gt], bias[gt]};
      acc[gt] = a;
    }

    // ---- x-GEMM: A from ring (or raw input), B from LDS ----
    const int bbase = (wu * 16 + l15) * 4 + l4;
    if (l == 0) {
      const float* xp = xin + ((size_t)mrowA * TSEQ + t) * INFEAT + l4 * 8;
#pragma unroll
      for (int kk = 0; kk < 4; ++kk) {          // kk 4..7 multiply the zero-pad
        bf16x8 axr = cvt8(xp + kk * 32);
#pragma unroll
        for (int gt = 0; gt < 4; ++gt) {
          bf16x8 b = lds_wih[gt * 1024 + kk * 128 + bbase];
          acc[gt] = __builtin_amdgcn_mfma_f32_16x16x32_bf16(axr, b, acc[gt], 0, 0, 0);
        }
      }
    } else {
      bf16x8 ax[8];
      const uint16_t* hp = hbX + ((size_t)(t & (DEPTH - 1)) * BATCH + mrowA) * HID + l4 * 8;
#pragma unroll
      for (int kk = 0; kk < 8; ++kk) ax[kk] = load_frag_dc(hp + kk * 32);
#pragma unroll
      for (int kk = 0; kk < 8; ++kk) {
#pragma unroll
        for (int gt = 0; gt < 4; ++gt) {
          bf16x8 b = lds_wih[gt * 1024 + kk * 128 + bbase];
          acc[gt] = __builtin_amdgcn_mfma_f32_16x16x32_bf16(ax[kk], b, acc[gt], 0, 0, 0);
        }
      }
    }

    // ---- h-GEMM: B register-resident ----
#pragma unroll
    for (int kk = 0; kk < 8; ++kk)
#pragma unroll
      for (int gt = 0; gt < 4; ++gt)
        acc[gt] = __builtin_amdgcn_mfma_f32_16x16x32_bf16(ah[kk], wh[gt][kk], acc[gt], 0, 0, 0);

    // ---- backpressure: consumer layer done with the slot we overwrite ----
    if (l < 5 && t >= DEPTH) {
      const uint8_t* fc = fCr + (size_t)(t - DEPTH) * 32 + wm * 16;
      while (!rec_half(fc)) __builtin_amdgcn_s_sleep(2);
    }

    // ---- gates, state update, h store (device-coherent) ----
    uint16_t* op = hbO + (size_t)(t & (DEPTH - 1)) * BATCH * HID;
#pragma unroll
    for (int j = 0; j < 4; ++j) {
      float iv = sigm(acc[0][j]);
      float fv = sigm(acc[1][j]);
      float gv = tanhff(acc[2][j]);
      float ov = sigm(acc[3][j]);
      float cc = fv * c[j] + iv * gv;
      c[j] = cc;
      float hv = ov * tanhff(cc);
      store_u16_dc(op + (size_t)(mrow0 + j) * HID + ucol, (uint16_t)f2bf(hv));
    }
    // per-wave drain then per-wave flag: no barrier on the signal path
    asm volatile("s_waitcnt vmcnt(0)" ::: "memory");
    if (lane == 0)
      store_u8_dc(fOr + (size_t)t * 32 + fidx, (uint8_t)1);
  }

  // ---------------- FC head: one WG per batch slice ----------------
  if (l == 5 && cg == 0) {
    const uint8_t* fl = fOr + (size_t)(TSEQ - 1) * 32;
    while (!(rec_half(fl) && rec_half(fl + 16))) __builtin_amdgcn_s_sleep(1);
    const uint16_t* hp = hbL + (size_t)((TSEQ - 1) & (DEPTH - 1)) * BATCH * HID;
    for (int p = tid; p < 32 * OUTN; p += 256) {
      const int mr = bs * 32 + p / OUTN, oc = p % OUTN;
      float a = fcb[oc];
      const uint16_t* hr = hp + (size_t)mr * HID;
      const float* wr = fcw + oc * HID;
#pragma unroll
      for (int uu = 0; uu < HID; uu += 4) {
        unsigned long long q = __hip_atomic_load((const unsigned long long*)(hr + uu),
                                                 __ATOMIC_RELAXED, __HIP_MEMORY_SCOPE_AGENT);
        a += bf2f((uint32_t)(q & 0xffff))         * wr[uu]
           + bf2f((uint32_t)((q >> 16) & 0xffff)) * wr[uu + 1]
           + bf2f((uint32_t)((q >> 32) & 0xffff)) * wr[uu + 2]
           + bf2f((uint32_t)(q >> 48))            * wr[uu + 3];
      }
      out[mr * OUTN + oc] = a;
    }
  }
}

extern "C" void kernel_launch(void* const* d_in, const int* in_sizes, int n_in,
                              void* d_out, int out_size, void* d_ws, size_t ws_size,
                              hipStream_t stream) {
  const float* xin = (const float*)d_in[0];
  const float* h0  = (const float*)d_in[1];
  const float* c0  = (const float*)d_in[2];
  const float* wih = (const float*)d_in[3];
  const float* whh = (const float*)d_in[4];
  const float* bih = (const float*)d_in[5];
  const float* bhh = (const float*)d_in[6];
  const float* fcw = (const float*)d_in[7];
  const float* fcb = (const float*)d_in[8];
  float* out = (float*)d_out;

  // flags: 24 groups x 512 t x 32 u8 = 384 KB, zeroed each launch
  uint8_t* flags = (uint8_t*)d_ws;
  const size_t flagBytes = (size_t)24 * TSEQ * 32;
  uint16_t* hbuf = (uint16_t*)((char*)d_ws + 0x80000);   // 512KB offset; 3.1MB ring

  hipMemsetAsync(d_ws, 0, flagBytes, stream);
  lstm_pipeline<<<dim3(192), dim3(256), 0, stream>>>(
      xin, h0, c0, wih, whh, bih, bhh, fcw, fcb, out, flags, hbuf);
}